// Round 1
// baseline (337.868 us; speedup 1.0000x reference)
//
#include <hip/hip_runtime.h>
#include <math.h>

#define B_   256
#define S_   4
#define W1_  64
#define W2_  128
#define D_   300
#define HID_ 4
#define KT   60     // K tile: 300 = 5 * 60
#define NKT  5
#define PADK 64     // padded LDS row stride (floats): 16 granules of 16B, power-of-2 for XOR swizzle

// Per-(b,s) similarity + threshold count kernel.
// Block = one (b,s) slot. Compacts active rows (mask==1) first, loads ONLY
// active rows, computes ONLY active x active dot products.
__global__ __launch_bounds__(256) void sim_count_kernel(
    const float* __restrict__ t1, const float* __restrict__ t2,
    const int* __restrict__ m1, const int* __restrict__ m2,
    const float* __restrict__ thr_p, float* __restrict__ norm_out)
{
    __shared__ float As[W1_ * PADK];   // 16 KB
    __shared__ float Bs[W2_ * PADK];   // 32 KB
    __shared__ int widx[W1_];
    __shared__ int vidx[W2_];
    __shared__ int cntA, cntB, cntOv;

    const int bs  = blockIdx.x;        // b*S + s
    const int tid = threadIdx.x;
    const float thr = *thr_p;

    if (tid == 0) { cntA = 0; cntB = 0; cntOv = 0; }
    __syncthreads();

    // --- compaction: build active-row index lists (order irrelevant, we only count) ---
    if (tid < W1_) {
        if (m1[bs * W1_ + tid] != 0) {
            int p = atomicAdd(&cntA, 1);
            widx[p] = tid;
        }
    } else if (tid < W1_ + W2_) {
        int v = tid - W1_;
        if (m2[bs * W2_ + v] != 0) {
            int p = atomicAdd(&cntB, 1);
            vidx[p] = v;
        }
    }
    __syncthreads();

    const int nA = cntA, nB = cntB;
    const int Ra = (nA + 3) >> 2;      // active 4-row tiles
    const int Cb = (nB + 7) >> 3;      // active 8-col tiles
    const int Ta = Ra * Cb;            // total active output tiles (<= 256)

    // Linearized tile assignment: first Ta threads get tiles -> idle lanes are
    // wave-contiguous, dead waves skip the FMA loop entirely.
    int tr = 0, tc = 0;
    const bool active = (tid < Ta);
    if (active) { tr = tid / Cb; tc = tid - tr * Cb; }
    const int swa = tr & 7;            // A swizzle bits: (w>>2)&7 with w=4*tr+i
    const int swb = tc & 7;            // B swizzle bits: (v>>3)&7 with v=8*tc+j

    float acc[4][8];
    #pragma unroll
    for (int i = 0; i < 4; ++i)
        #pragma unroll
        for (int j = 0; j < 8; ++j) acc[i][j] = 0.f;

    const float* t1b = t1 + (size_t)bs * W1_ * D_;
    const float* t2b = t2 + (size_t)bs * W2_ * D_;

    for (int kt = 0; kt < NKT; ++kt) {
        const int k0 = kt * KT;
        // --- stage active A rows (coalesced float4, XOR-swizzled granule) ---
        for (int idx = tid; idx < nA * (KT / 4); idx += 256) {
            int a = idx / (KT / 4);
            int f = idx - a * (KT / 4);
            const float4 val = *reinterpret_cast<const float4*>(
                t1b + (size_t)widx[a] * D_ + k0 + 4 * f);
            *reinterpret_cast<float4*>(
                &As[a * PADK + 4 * (f ^ ((a >> 2) & 7))]) = val;
        }
        // --- stage active B rows ---
        for (int idx = tid; idx < nB * (KT / 4); idx += 256) {
            int v = idx / (KT / 4);
            int f = idx - v * (KT / 4);
            const float4 val = *reinterpret_cast<const float4*>(
                t2b + (size_t)vidx[v] * D_ + k0 + 4 * f);
            *reinterpret_cast<float4*>(
                &Bs[v * PADK + 4 * (f ^ ((v >> 3) & 7))]) = val;
        }
        __syncthreads();

        if (active) {
            #pragma unroll
            for (int g = 0; g < KT / 4; ++g) {
                float4 av[4];
                float4 bv[8];
                #pragma unroll
                for (int i = 0; i < 4; ++i)
                    av[i] = *reinterpret_cast<const float4*>(
                        &As[(4 * tr + i) * PADK + 4 * (g ^ swa)]);
                #pragma unroll
                for (int j = 0; j < 8; ++j)
                    bv[j] = *reinterpret_cast<const float4*>(
                        &Bs[(8 * tc + j) * PADK + 4 * (g ^ swb)]);
                #pragma unroll
                for (int i = 0; i < 4; ++i)
                    #pragma unroll
                    for (int j = 0; j < 8; ++j) {
                        acc[i][j] = fmaf(av[i].x, bv[j].x, acc[i][j]);
                        acc[i][j] = fmaf(av[i].y, bv[j].y, acc[i][j]);
                        acc[i][j] = fmaf(av[i].z, bv[j].z, acc[i][j]);
                        acc[i][j] = fmaf(av[i].w, bv[j].w, acc[i][j]);
                    }
            }
        }
        __syncthreads();   // before next tile overwrites LDS
    }

    // --- threshold count over valid (active) outputs only ---
    int lc = 0;
    if (active) {
        int ilim = nA - 4 * tr; if (ilim > 4) ilim = 4;
        int jlim = nB - 8 * tc; if (jlim > 8) jlim = 8;
        for (int i = 0; i < ilim; ++i)
            for (int j = 0; j < jlim; ++j)
                lc += (acc[i][j] >= thr) ? 1 : 0;
    }
    // wave reduce then one LDS atomic per wave
    #pragma unroll
    for (int o = 32; o > 0; o >>= 1) lc += __shfl_down(lc, o);
    if ((tid & 63) == 0 && lc != 0) atomicAdd(&cntOv, lc);
    __syncthreads();

    if (tid == 0) {
        float divisor = (nA == 0) ? 1e-7f : (float)nA;
        norm_out[bs] = (float)cntOv / divisor;
    }
}

// Tiny MLP head: h = tanh(norm @ Wh), out = sigmoid(h @ Ws)
__global__ __launch_bounds__(256) void head_kernel(
    const float* __restrict__ norm,
    const float* __restrict__ Wh,   // (S, HID) row-major
    const float* __restrict__ Ws,   // (HID, 1)
    float* __restrict__ out)
{
    int b = blockIdx.x * blockDim.x + threadIdx.x;
    if (b >= B_) return;
    float4 n = *reinterpret_cast<const float4*>(norm + b * 4);
    float score = 0.f;
    #pragma unroll
    for (int j = 0; j < HID_; ++j) {
        float h = n.x * Wh[0 * HID_ + j] + n.y * Wh[1 * HID_ + j]
                + n.z * Wh[2 * HID_ + j] + n.w * Wh[3 * HID_ + j];
        h = tanhf(h);
        score += h * Ws[j];
    }
    out[b] = 1.f / (1.f + expf(-score));
}

extern "C" void kernel_launch(void* const* d_in, const int* in_sizes, int n_in,
                              void* d_out, int out_size, void* d_ws, size_t ws_size,
                              hipStream_t stream)
{
    const float* t1  = (const float*)d_in[0];
    const float* t2  = (const float*)d_in[1];
    const int*   m1  = (const int*)d_in[2];
    const int*   m2  = (const int*)d_in[3];
    const float* thr = (const float*)d_in[4];
    const float* Wh  = (const float*)d_in[5];
    const float* Ws  = (const float*)d_in[6];
    float* out  = (float*)d_out;
    float* norm = (float*)d_ws;   // 1024 floats

    sim_count_kernel<<<B_ * S_, 256, 0, stream>>>(t1, t2, m1, m2, thr, norm);
    head_kernel<<<1, 256, 0, stream>>>(norm, Wh, Ws, out);
}

// Round 2
// 313.019 us; speedup vs baseline: 1.0794x; 1.0794x over previous
//
#include <hip/hip_runtime.h>
#include <math.h>

#define B_   256
#define S_   4
#define W1_  64
#define W2_  128
#define D_   300
#define HID_ 4
#define KT   60     // K tile: 300 = 5 * 60
#define NKT  5
#define PADK 64     // padded LDS row stride (floats): 16 granules of 16B, power-of-2 for XOR swizzle

// Per-(b,s) similarity + threshold count kernel.
// Block = one (b,s) slot. Compacts active rows (mask==1) first, loads ONLY
// active rows, computes ONLY active x active dot products.
__global__ __launch_bounds__(256) void sim_count_kernel(
    const float* __restrict__ t1, const float* __restrict__ t2,
    const int* __restrict__ m1, const int* __restrict__ m2,
    const float* __restrict__ thr_p, float* __restrict__ norm_out)
{
    __shared__ float As[W1_ * PADK];   // 16 KB
    __shared__ float Bs[W2_ * PADK];   // 32 KB
    __shared__ int widx[W1_];
    __shared__ int vidx[W2_];
    __shared__ int cntA, cntB, cntOv;

    const int bs  = blockIdx.x;        // b*S + s
    const int tid = threadIdx.x;
    const float thr = *thr_p;

    if (tid == 0) { cntA = 0; cntB = 0; cntOv = 0; }
    __syncthreads();

    // --- compaction: build active-row index lists (order irrelevant, we only count) ---
    if (tid < W1_) {
        if (m1[bs * W1_ + tid] != 0) {
            int p = atomicAdd(&cntA, 1);
            widx[p] = tid;
        }
    } else if (tid < W1_ + W2_) {
        int v = tid - W1_;
        if (m2[bs * W2_ + v] != 0) {
            int p = atomicAdd(&cntB, 1);
            vidx[p] = v;
        }
    }
    __syncthreads();

    const int nA = cntA, nB = cntB;
    const int Ra = (nA + 3) >> 2;      // active 4-row tiles
    const int Cb = (nB + 7) >> 3;      // active 8-col tiles
    const int Ta = Ra * Cb;            // total active output tiles (<= 256)

    // Linearized tile assignment: first Ta threads get tiles -> idle lanes are
    // wave-contiguous, dead waves skip the FMA loop entirely.
    int tr = 0, tc = 0;
    const bool active = (tid < Ta);
    if (active) { tr = tid / Cb; tc = tid - tr * Cb; }
    const int swa = tr & 7;            // A swizzle bits: (w>>2)&7 with w=4*tr+i
    const int swb = tc & 7;            // B swizzle bits: (v>>3)&7 with v=8*tc+j

    // NOTE: every access to acc below uses compile-time indices only (fully
    // unrolled loops) — runtime indexing would demote it to scratch (rule #20;
    // round-1 showed 70 MB of HBM writes from exactly that).
    float acc[4][8];
    #pragma unroll
    for (int i = 0; i < 4; ++i)
        #pragma unroll
        for (int j = 0; j < 8; ++j) acc[i][j] = 0.f;

    const float* t1b = t1 + (size_t)bs * W1_ * D_;
    const float* t2b = t2 + (size_t)bs * W2_ * D_;

    for (int kt = 0; kt < NKT; ++kt) {
        const int k0 = kt * KT;
        // --- stage active A rows (coalesced float4, XOR-swizzled granule) ---
        for (int idx = tid; idx < nA * (KT / 4); idx += 256) {
            int a = idx / (KT / 4);
            int f = idx - a * (KT / 4);
            const float4 val = *reinterpret_cast<const float4*>(
                t1b + (size_t)widx[a] * D_ + k0 + 4 * f);
            *reinterpret_cast<float4*>(
                &As[a * PADK + 4 * (f ^ ((a >> 2) & 7))]) = val;
        }
        // --- stage active B rows ---
        for (int idx = tid; idx < nB * (KT / 4); idx += 256) {
            int v = idx / (KT / 4);
            int f = idx - v * (KT / 4);
            const float4 val = *reinterpret_cast<const float4*>(
                t2b + (size_t)vidx[v] * D_ + k0 + 4 * f);
            *reinterpret_cast<float4*>(
                &Bs[v * PADK + 4 * (f ^ ((v >> 3) & 7))]) = val;
        }
        __syncthreads();

        if (active) {
            #pragma unroll
            for (int g = 0; g < KT / 4; ++g) {
                float4 av[4];
                float4 bv[8];
                #pragma unroll
                for (int i = 0; i < 4; ++i)
                    av[i] = *reinterpret_cast<const float4*>(
                        &As[(4 * tr + i) * PADK + 4 * (g ^ swa)]);
                #pragma unroll
                for (int j = 0; j < 8; ++j)
                    bv[j] = *reinterpret_cast<const float4*>(
                        &Bs[(8 * tc + j) * PADK + 4 * (g ^ swb)]);
                #pragma unroll
                for (int i = 0; i < 4; ++i)
                    #pragma unroll
                    for (int j = 0; j < 8; ++j) {
                        acc[i][j] = fmaf(av[i].x, bv[j].x, acc[i][j]);
                        acc[i][j] = fmaf(av[i].y, bv[j].y, acc[i][j]);
                        acc[i][j] = fmaf(av[i].z, bv[j].z, acc[i][j]);
                        acc[i][j] = fmaf(av[i].w, bv[j].w, acc[i][j]);
                    }
            }
        }
        __syncthreads();   // before next tile overwrites LDS
    }

    // --- threshold count over valid (active) outputs only ---
    // Fully unrolled, compile-time acc indices; validity via predication.
    int lc = 0;
    if (active) {
        const int ilim = min(nA - 4 * tr, 4);
        const int jlim = min(nB - 8 * tc, 8);
        #pragma unroll
        for (int i = 0; i < 4; ++i)
            #pragma unroll
            for (int j = 0; j < 8; ++j)
                lc += ((i < ilim) & (j < jlim) & (acc[i][j] >= thr)) ? 1 : 0;
    }
    // wave reduce then one LDS atomic per wave
    #pragma unroll
    for (int o = 32; o > 0; o >>= 1) lc += __shfl_down(lc, o);
    if ((tid & 63) == 0 && lc != 0) atomicAdd(&cntOv, lc);
    __syncthreads();

    if (tid == 0) {
        float divisor = (nA == 0) ? 1e-7f : (float)nA;
        norm_out[bs] = (float)cntOv / divisor;
    }
}

// Tiny MLP head: h = tanh(norm @ Wh), out = sigmoid(h @ Ws)
__global__ __launch_bounds__(256) void head_kernel(
    const float* __restrict__ norm,
    const float* __restrict__ Wh,   // (S, HID) row-major
    const float* __restrict__ Ws,   // (HID, 1)
    float* __restrict__ out)
{
    int b = blockIdx.x * blockDim.x + threadIdx.x;
    if (b >= B_) return;
    float4 n = *reinterpret_cast<const float4*>(norm + b * 4);
    float score = 0.f;
    #pragma unroll
    for (int j = 0; j < HID_; ++j) {
        float h = n.x * Wh[0 * HID_ + j] + n.y * Wh[1 * HID_ + j]
                + n.z * Wh[2 * HID_ + j] + n.w * Wh[3 * HID_ + j];
        h = tanhf(h);
        score += h * Ws[j];
    }
    out[b] = 1.f / (1.f + expf(-score));
}

extern "C" void kernel_launch(void* const* d_in, const int* in_sizes, int n_in,
                              void* d_out, int out_size, void* d_ws, size_t ws_size,
                              hipStream_t stream)
{
    const float* t1  = (const float*)d_in[0];
    const float* t2  = (const float*)d_in[1];
    const int*   m1  = (const int*)d_in[2];
    const int*   m2  = (const int*)d_in[3];
    const float* thr = (const float*)d_in[4];
    const float* Wh  = (const float*)d_in[5];
    const float* Ws  = (const float*)d_in[6];
    float* out  = (float*)d_out;
    float* norm = (float*)d_ws;   // 1024 floats

    sim_count_kernel<<<B_ * S_, 256, 0, stream>>>(t1, t2, m1, m2, thr, norm);
    head_kernel<<<1, 256, 0, stream>>>(norm, Wh, Ws, out);
}